// Round 7
// baseline (687.268 us; speedup 1.0000x reference)
//
#include <hip/hip_runtime.h>
#include <hip/hip_fp16.h>
#include <cstdint>
#include <cstring>

// VQR circuit simulator: 16 qubits, B=512, 4 layers.
// CNOTs are GF(2) index-relabeling bookkeeping. Fused 1q gates (SU(2)) are
// XOR-mask pair rotations, scheduled into 2 window passes
// (gen+gates+store, load+gates+measure). Within a pass, bundles of <=3
// mask-independent gates + the e0 pack axis: each thread holds a dim-4 coset
// as 8 complex v2f pairs (SoA re/im LDS), applying gates with packed-fp32
// (v_pk_fma_f32) math: 8 FMA-instructions per amp-pair instead of 16.
// Gate coefficients are computed in-block (no precompute kernel).

typedef float v2f __attribute__((ext_vector_type(2)));

struct BundleMeta {
    uint16_t voffE[8];   // even coset offsets per slot (bit0 cleared)
    uint16_t row[3];     // branch parity masks (local bits)
    uint8_t  fpar[3];    // bit t = parity(voffE[t] & row[g])
    uint8_t  nl[3];      // branch parity masks over chunk bits
    uint8_t  gidx[3];    // gate coefficient index l*16+w; 0xFF = pad
    uint8_t  flags[3];   // bit0 = row&1 (half-sign), bit1 = mask&1 (swap)
    uint8_t  piv[4];     // pivot bit positions ASCENDING (includes bit 0)
    uint8_t  _pad[2];
};

struct PassMeta {
    int        nbundles;
    BundleMeta bd[22];
    uint8_t    gap[4];          // non-local bit positions, ASCENDING (all >=8)
    uint8_t    nlw[4];          // chunk bit k -> wire
    uint8_t    wire_of_bit[12]; // packed LDS bit -> wire (product-state init)
    uint16_t   meas_row;        // measurement parity mask (local bits)
    uint8_t    meas_nl;         // measurement parity mask (chunk bits)
};

__device__ __forceinline__ float xorf(float a, unsigned s) {
    return __uint_as_float(__float_as_uint(a) ^ s);
}
__device__ __forceinline__ float2 cmul2(float2 a, float2 b) {
    return make_float2(a.x * b.x - a.y * b.y, a.x * b.y + a.y * b.x);
}

// MODE 0: coef + product state + gates + store (fp16)
// MODE 1: coef + load + gates + store (in-place, fp16)
// MODE 2: coef + load + gates + measurement reduce (no store)
template <int MODE>
__global__ __launch_bounds__(256, 4)
void pass_kernel(const float* __restrict__ X, const float* __restrict__ Wt,
                 const float* __restrict__ Bs, __half2* __restrict__ state,
                 float* __restrict__ out, PassMeta meta)
{
    __shared__ float  reS[4096];   // 16 KiB
    __shared__ float  imS[4096];   // 16 KiB
    __shared__ float4 coef[64];    // 1 KiB  (SU(2) (a,b) per gate)
    const int tid = threadIdx.x;
    const int bb  = blockIdx.x >> 4;
    const unsigned c = blockIdx.x & 15u;
    const size_t base = (size_t)bb << 16;

    // ---- in-block coefficient computation: U = Rz(t2)Ry(t1)Rz(t0)Rx(2atan x)
    if (tid < 64) {
        int l = tid >> 4, w = tid & 15;
        float x  = X[bb * 16 + w];
        float ce = 1.0f / sqrtf(1.0f + x * x);
        float se = x * ce;
        float t0 = 0.5f * Wt[(l * 16 + w) * 3 + 0];
        float t1 = 0.5f * Wt[(l * 16 + w) * 3 + 1];
        float t2 = 0.5f * Wt[(l * 16 + w) * 3 + 2];
        float c1 = cosf(t1), s1 = sinf(t1);
        float ca = cosf(t0 + t2), sa = sinf(t0 + t2);
        float cb = cosf(t2 - t0), sb = sinf(t2 - t0);
        float2 W00 = make_float2( c1 * ca, -c1 * sa);
        float2 W01 = make_float2(-s1 * cb,  s1 * sb);
        float2 a  = make_float2(W00.x * ce + W01.y * se, W00.y * ce - W01.x * se);
        float2 b2 = make_float2(W00.y * se + W01.x * ce, -W00.x * se + W01.y * ce);
        coef[tid] = make_float4(a.x, a.y, b2.x, b2.y);
    }
    if (MODE == 0 && c == 0 && tid == 64) out[bb] = Bs[0];  // bias init (runs before MODE2)

    auto expand = [&](unsigned x) -> unsigned {   // gaps ascending, all >= 8
        #pragma unroll
        for (int k = 0; k < 4; ++k) {
            unsigned g = meta.gap[k];
            x = ((x >> g) << (g + 1)) | (x & ((1u << g) - 1u)) | (((c >> k) & 1u) << g);
        }
        return x;
    };

    if constexpr (MODE == 0) {
        __syncthreads();   // coef ready
        if (tid == 0) {
            float2 k = make_float2(1.f, 0.f);
            #pragma unroll
            for (int t = 0; t < 4; ++t) {
                float4 u = coef[meta.nlw[t]];
                float2 col = ((c >> t) & 1u) ? make_float2(-u.z, u.w)
                                             : make_float2(u.x, u.y);
                k = cmul2(k, col);
            }
            reS[0] = k.x; imS[0] = k.y;
        }
        __syncthreads();
        for (int s = 0; s < 12; ++s) {
            const int n = 1 << s;
            float4 u = coef[meta.wire_of_bit[s]];
            const float2 c0 = make_float2(u.x, u.y);
            const float2 c1 = make_float2(-u.z, u.w);
            for (int i = tid; i < n; i += 256) {
                float2 a = make_float2(reS[i], imS[i]);
                float2 h = cmul2(a, c1);
                float2 l = cmul2(a, c0);
                reS[i + n] = h.x; imS[i + n] = h.y;
                reS[i]     = l.x; imS[i]     = l.y;
            }
            __syncthreads();
        }
    } else {
        #pragma unroll
        for (int it = 0; it < 4; ++it) {
            unsigned u = (unsigned)(tid + it * 256) * 4u;
            unsigned a = expand(u);
            uint4 v = *reinterpret_cast<const uint4*>(state + base + a);
            float2 f0 = __half22float2(__builtin_bit_cast(__half2, v.x));
            float2 f1 = __half22float2(__builtin_bit_cast(__half2, v.y));
            float2 f2 = __half22float2(__builtin_bit_cast(__half2, v.z));
            float2 f3 = __half22float2(__builtin_bit_cast(__half2, v.w));
            *reinterpret_cast<float4*>(&reS[u]) = make_float4(f0.x, f1.x, f2.x, f3.x);
            *reinterpret_cast<float4*>(&imS[u]) = make_float4(f0.y, f1.y, f2.y, f3.y);
        }
        __syncthreads();   // also covers coef staging
    }

    for (int ci = 0; ci < meta.nbundles; ++ci) {
        const BundleMeta& B = meta.bd[ci];
        unsigned r = (unsigned)tid;
        #pragma unroll
        for (int k = 0; k < 4; ++k) {
            unsigned p = B.piv[k];
            r = ((r >> p) << (p + 1)) | (r & ((1u << p) - 1u));
        }
        v2f RE[8], IM[8];
        #pragma unroll
        for (int t = 0; t < 8; ++t) {
            unsigned j = r ^ B.voffE[t];
            RE[t] = *reinterpret_cast<const v2f*>(&reS[j]);
            IM[t] = *reinterpret_cast<const v2f*>(&imS[j]);
        }
        #pragma unroll
        for (int g = 0; g < 3; ++g) {
            if (B.gidx[g] == 0xFF) continue;     // pad slot (uniform skip)
            const float4 uv = coef[B.gidx[g]];
            const unsigned base31 =
                ((unsigned)((__popc(r & (unsigned)B.row[g]) +
                             __popc((unsigned)B.nl[g] & c)) & 1)) << 31;
            const float uai = xorf(uv.y, base31);
            const float ubr = xorf(uv.z, base31);
            const v2f ARv = {uv.x, uv.x};
            const v2f BIv = {uv.w, uv.w};
            const unsigned fpar = B.fpar[g];
            const unsigned ro31 = ((unsigned)(B.flags[g] & 1u)) << 31;
            const bool swp = (B.flags[g] & 2u) != 0;
            #pragma unroll
            for (int t = 0; t < 8; ++t) {
                if (t & (1 << g)) continue;
                const int t2 = t | (1 << g);
                const unsigned f31 = ((fpar >> t) & 1u) << 31;
                const v2f TAI = { xorf(uai, f31), xorf(uai, f31 ^ ro31) };
                const v2f TBR = { xorf(ubr, f31), xorf(ubr, f31 ^ ro31) };
                const v2f PR = RE[t], PI = IM[t];
                v2f QR = RE[t2], QI = IM[t2];
                if (swp) {
                    QR = __builtin_shufflevector(QR, QR, 1, 0);
                    QI = __builtin_shufflevector(QI, QI, 1, 0);
                }
                v2f NPR = ARv * PR - TAI * PI + TBR * QR - BIv * QI;
                v2f NPI = ARv * PI + TAI * PR + TBR * QI + BIv * QR;
                v2f NQR = ARv * QR + TAI * QI - TBR * PR - BIv * PI;
                v2f NQI = ARv * QI - TAI * QR - TBR * PI + BIv * PR;
                if (swp) {
                    NQR = __builtin_shufflevector(NQR, NQR, 1, 0);
                    NQI = __builtin_shufflevector(NQI, NQI, 1, 0);
                }
                RE[t] = NPR; IM[t] = NPI;
                RE[t2] = NQR; IM[t2] = NQI;
            }
        }
        if (MODE == 2 && ci == meta.nbundles - 1) {
            // measure directly from registers
            const unsigned mrow = meta.meas_row;
            const unsigned ro31 = (mrow & 1u) << 31;
            const unsigned mb31 =
                ((unsigned)(__popc((unsigned)meta.meas_nl & c) & 1)) << 31;
            v2f acc2 = {0.f, 0.f};
            #pragma unroll
            for (int t = 0; t < 8; ++t) {
                v2f pr = RE[t] * RE[t] + IM[t] * IM[t];
                unsigned s0 = (((unsigned)__popc((r ^ B.voffE[t]) & mrow) & 1u) << 31) ^ mb31;
                acc2 += v2f{ xorf(pr.x, s0), xorf(pr.y, s0 ^ ro31) };
            }
            float acc = acc2.x + acc2.y;
            for (int off = 32; off > 0; off >>= 1) acc += __shfl_down(acc, off, 64);
            if ((tid & 63) == 0) atomicAdd(&out[bb], acc);
            return;
        }
        #pragma unroll
        for (int t = 0; t < 8; ++t) {
            unsigned j = r ^ B.voffE[t];
            *reinterpret_cast<v2f*>(&reS[j]) = RE[t];
            *reinterpret_cast<v2f*>(&imS[j]) = IM[t];
        }
        __syncthreads();
    }

    if constexpr (MODE == 2) {
        // fallback (nbundles==0 only): measure from LDS
        float acc = 0.f;
        const unsigned mcp = (unsigned)(__popc((unsigned)meta.meas_nl & c) & 1);
        for (int k = 0; k < 16; ++k) {
            unsigned u = (unsigned)(tid + k * 256);
            float pr = reS[u] * reS[u] + imS[u] * imS[u];
            acc += (((unsigned)__popc(u & (unsigned)meta.meas_row) & 1u) ^ mcp)
                 ? -pr : pr;
        }
        for (int off = 32; off > 0; off >>= 1) acc += __shfl_down(acc, off, 64);
        if ((tid & 63) == 0) atomicAdd(&out[bb], acc);
    } else {
        #pragma unroll
        for (int it = 0; it < 4; ++it) {
            unsigned u = (unsigned)(tid + it * 256) * 4u;
            unsigned ad = expand(u);
            float4 rr = *reinterpret_cast<const float4*>(&reS[u]);
            float4 ii = *reinterpret_cast<const float4*>(&imS[u]);
            uint4 v;
            v.x = __builtin_bit_cast(unsigned, __float22half2_rn(make_float2(rr.x, ii.x)));
            v.y = __builtin_bit_cast(unsigned, __float22half2_rn(make_float2(rr.y, ii.y)));
            v.z = __builtin_bit_cast(unsigned, __float22half2_rn(make_float2(rr.z, ii.z)));
            v.w = __builtin_bit_cast(unsigned, __float22half2_rn(make_float2(rr.w, ii.w)));
            *reinterpret_cast<uint4*>(state + base + ad) = v;
        }
    }
}

extern "C" void kernel_launch(void* const* d_in, const int* in_sizes, int n_in,
                              void* d_out, int out_size, void* d_ws, size_t ws_size,
                              hipStream_t stream)
{
    const float* X  = (const float*)d_in[0];
    const float* Wt = (const float*)d_in[1];
    const float* Bs = (const float*)d_in[2];
    float* out = (float*)d_out;
    __half2* state = (__half2*)d_ws;

    int group = 1;   // fp16 state: 256 KiB per batch element
    while (group < 512 && (size_t)(group * 2) * (65536ull * 4) <= ws_size)
        group <<= 1;
    const int ngroups = 512 / group;

    // ---- GF(2) bookkeeping (sequential CNOT ring, matches reference) ----
    uint16_t D[16], R[16];
    for (int w = 0; w < 16; ++w) { D[w] = R[w] = (uint16_t)(1u << w); }
    struct G { uint16_t D, R; uint8_t gidx; bool kept; bool sched; };
    G gl[48]; int ng = 0;
    for (int l = 1; l <= 3; ++l) {
        for (int w = 0; w < 16; ++w) { int t = (w + 1) & 15; D[w] ^= D[t]; R[t] ^= R[w]; }
        for (int w = 0; w < 16; ++w)
            gl[ng++] = G{D[w], R[w], (uint8_t)(l * 16 + w), true, false};
    }
    for (int w = 0; w < 16; ++w) { int t = (w + 1) & 15; D[w] ^= D[t]; R[t] ^= R[w]; }
    const uint16_t Rmeas = R[0];

    // Backward prune
    {
        uint16_t keptD[49], keptR[49]; int nk = 0;
        keptD[nk] = 0; keptR[nk] = Rmeas; ++nk;
        for (int i = ng - 1; i >= 0; --i) {
            bool comm = true;
            for (int k = 0; k < nk; ++k) {
                if (__builtin_parity((unsigned)(gl[i].D & keptR[k])) ||
                    __builtin_parity((unsigned)(keptD[k] & gl[i].R))) { comm = false; break; }
            }
            if (comm) gl[i].kept = false;
            else { keptD[nk] = gl[i].D; keptR[nk] = gl[i].R; ++nk; }
        }
    }
    int nkept = 0;
    for (int i = 0; i < ng; ++i) if (gl[i].kept) ++nkept;

    auto commute = [&](int i, int j) -> bool {
        return !(__builtin_parity((unsigned)(gl[i].D & gl[j].R)) ||
                 __builtin_parity((unsigned)(gl[j].D & gl[i].R)));
    };

    const int MAXP = 8;
    auto simulate = [&](uint16_t SA, uint16_t SB, int* passOf) -> int {
        for (int i = 0; i < ng; ++i) gl[i].sched = false;
        int rem = nkept, np = 0, stall = 0;
        while (rem > 0 && np < MAXP) {
            uint16_t S = (np & 1) ? SB : SA;
            int got = 0;
            for (int i = 0; i < ng; ++i) {
                if (!gl[i].kept || gl[i].sched) continue;
                if (gl[i].D & S) continue;
                bool ok = true;
                for (int j = 0; j < i; ++j) {
                    if (!gl[j].kept || gl[j].sched) continue;
                    if (!commute(i, j)) { ok = false; break; }
                }
                if (!ok) continue;
                gl[i].sched = true; --rem; ++got;
                if (passOf) passOf[i] = np;
            }
            ++np;
            if (got == 0) { if (++stall >= 2) break; } else stall = 0;
        }
        return rem == 0 ? np : 99;
    };

    // Window-pair search (4 excluded wires per window, consecutive runs)
    int bestNp = 99, bestA = 0, bestB = 8;
    for (int a = 0; a < 16; ++a) {
        for (int b = 0; b < 16; ++b) {
            uint16_t SA = 0, SB = 0;
            for (int k = 0; k < 4; ++k) {
                SA |= (uint16_t)(1u << ((a + k) & 15));
                SB |= (uint16_t)(1u << ((b + k) & 15));
            }
            int np = simulate(SA, SB, nullptr);
            if (np < bestNp) { bestNp = np; bestA = a; bestB = b; }
        }
    }
    uint16_t SA = 0, SB = 0;
    int exA[4], exB[4];
    for (int k = 0; k < 4; ++k) {
        exA[k] = (bestA + k) & 15; exB[k] = (bestB + k) & 15;
        SA |= (uint16_t)(1u << exA[k]); SB |= (uint16_t)(1u << exB[k]);
    }
    int passOf[48];
    for (int i = 0; i < ng; ++i) passOf[i] = -1;
    int np = simulate(SA, SB, passOf);
    if (np > MAXP) np = MAXP;
    if (np < 2) np = 2;

    // Wire -> bit position: all excluded wires at positions >= 8.
    int wireToPos[16]; bool used[16] = {};
    int pos = 15;
    for (int k = 0; k < 4; ++k) { wireToPos[exA[k]] = pos--; used[exA[k]] = true; }
    for (int k = 0; k < 4; ++k)
        if (!used[exB[k]]) { wireToPos[exB[k]] = pos--; used[exB[k]] = true; }
    for (int w = 0; w < 16; ++w) if (!used[w]) wireToPos[w] = pos--;
    int posToWire[16];
    for (int w = 0; w < 16; ++w) posToWire[wireToPos[w]] = w;

    PassMeta pms[8];
    for (int p = 0; p < np; ++p) {
        PassMeta& M = pms[p];
        memset(&M, 0, sizeof(M));
        const int* ex = (p & 1) ? exB : exA;
        int gp[4], gw[4];
        for (int k = 0; k < 4; ++k) { gp[k] = wireToPos[ex[k]]; gw[k] = ex[k]; }
        for (int a2 = 0; a2 < 4; ++a2)
            for (int b2 = a2 + 1; b2 < 4; ++b2)
                if (gp[b2] < gp[a2]) {
                    int t = gp[a2]; gp[a2] = gp[b2]; gp[b2] = t;
                    t = gw[a2]; gw[a2] = gw[b2]; gw[b2] = t;
                }
        for (int k = 0; k < 4; ++k) { M.gap[k] = (uint8_t)gp[k]; M.nlw[k] = (uint8_t)gw[k]; }
        int packedOfWire[16];
        for (int w = 0; w < 16; ++w) packedOfWire[w] = -1;
        int t = 0;
        for (int q = 0; q < 16; ++q) {
            bool isgap = false;
            for (int k = 0; k < 4; ++k) if (q == gp[k]) isgap = true;
            if (isgap) continue;
            M.wire_of_bit[t] = (uint8_t)posToWire[q];
            packedOfWire[posToWire[q]] = t;
            ++t;
        }
        // local gate list, schedule order
        struct LG { uint16_t m, r; uint8_t nl, gidx; };
        LG ls[48]; int nsel = 0;
        for (int i = 0; i < ng; ++i) {
            if (!gl[i].kept || passOf[i] != p) continue;
            uint16_t m = 0, r = 0; uint8_t nl = 0;
            for (int w = 0; w < 16; ++w) {
                if ((gl[i].D >> w) & 1) m |= (uint16_t)(1u << packedOfWire[w]);
                if (((gl[i].R >> w) & 1) && packedOfWire[w] >= 0)
                    r |= (uint16_t)(1u << packedOfWire[w]);
            }
            for (int k = 0; k < 4; ++k)
                if ((gl[i].R >> gw[k]) & 1) nl |= (uint8_t)(1u << k);
            ls[nsel++] = LG{m, r, nl, gl[i].gidx};
        }
        // Bundle consecutive gates: basis seeded with e0 (the pack axis);
        // close when the next mask is dependent or 3 slots filled.
        M.nbundles = 0;
        int s = 0;
        while (s < nsel && M.nbundles < 22) {
            BundleMeta& B = M.bd[M.nbundles++];
            memset(&B, 0, sizeof(B));
            for (int j = 0; j < 3; ++j) B.gidx[j] = 0xFF;
            uint16_t red[4]; int pv[4]; int nb = 1;
            red[0] = 1; pv[0] = 0;                 // e0 pack axis
            uint16_t mraw[3] = {0, 0, 0};
            int nsl = 0;
            while (nsl < 3 && s < nsel) {
                uint16_t r0 = ls[s].m;
                for (int j = 0; j < nb; ++j)
                    if ((r0 >> pv[j]) & 1) r0 ^= red[j];
                if (!r0) break;                    // dependent -> close bundle
                pv[nb] = 31 - __builtin_clz((unsigned)r0);
                red[nb] = r0; ++nb;
                mraw[nsl] = ls[s].m;
                B.gidx[nsl] = ls[s].gidx;
                B.row[nsl]  = ls[s].r;
                B.nl[nsl]   = ls[s].nl;
                B.flags[nsl] = (uint8_t)((ls[s].r & 1u) | ((ls[s].m & 1u) << 1));
                ++nsl; ++s;
            }
            for (int b = 11; b >= 1 && nb < 4; --b) {   // pad basis (never bit 0)
                uint16_t r0 = (uint16_t)(1u << b);
                for (int j = 0; j < nb; ++j)
                    if ((r0 >> pv[j]) & 1) r0 ^= red[j];
                if (!r0) continue;
                pv[nb] = 31 - __builtin_clz((unsigned)r0);
                red[nb] = r0; ++nb;
                mraw[nsl] = (uint16_t)(1u << b);   // pad slot mask (no gate)
                ++nsl;
            }
            for (int tt = 0; tt < 8; ++tt) {
                uint16_t v = 0;
                for (int j = 0; j < 3; ++j) if ((tt >> j) & 1) v ^= mraw[j];
                B.voffE[tt] = (uint16_t)(v & ~1u);
            }
            for (int j = 0; j < 3; ++j) {
                if (B.gidx[j] == 0xFF) continue;
                uint8_t f = 0;
                for (int tt = 0; tt < 8; ++tt)
                    if (__builtin_parity((unsigned)(B.voffE[tt] & B.row[j])))
                        f |= (uint8_t)(1u << tt);
                B.fpar[j] = f;
            }
            for (int a2 = 0; a2 < 4; ++a2)
                for (int b2 = a2 + 1; b2 < 4; ++b2)
                    if (pv[b2] < pv[a2]) { int tt = pv[a2]; pv[a2] = pv[b2]; pv[b2] = tt; }
            for (int j = 0; j < 4; ++j) B.piv[j] = (uint8_t)pv[j];
        }
        {   // measurement masks (used only if this pass is last)
            uint16_t r = 0; uint8_t nl = 0;
            for (int w = 0; w < 16; ++w)
                if (((Rmeas >> w) & 1) && packedOfWire[w] >= 0)
                    r |= (uint16_t)(1u << packedOfWire[w]);
            for (int k = 0; k < 4; ++k)
                if ((Rmeas >> gw[k]) & 1) nl |= (uint8_t)(1u << k);
            M.meas_row = r; M.meas_nl = nl;
        }
    }

    for (int g = 0; g < ngroups; ++g) {
        const float* Xg = X + (size_t)g * group * 16;
        __half2* st = state;
        float* og = out + (size_t)g * group;
        dim3 grid((unsigned)(group << 4));
        for (int p = 0; p < np; ++p) {
            int mode = (p == 0) ? 0 : ((p == np - 1) ? 2 : 1);
            if (mode == 0)
                pass_kernel<0><<<grid, dim3(256), 0, stream>>>(Xg, Wt, Bs, st, og, pms[p]);
            else if (mode == 1)
                pass_kernel<1><<<grid, dim3(256), 0, stream>>>(Xg, Wt, Bs, st, og, pms[p]);
            else
                pass_kernel<2><<<grid, dim3(256), 0, stream>>>(Xg, Wt, Bs, st, og, pms[p]);
        }
    }

    (void)in_sizes; (void)n_in; (void)out_size; (void)ws_size;
}

// Round 8
// 546.821 us; speedup vs baseline: 1.2568x; 1.2568x over previous
//
#include <hip/hip_runtime.h>
#include <hip/hip_fp16.h>
#include <cstdint>
#include <cstring>

// VQR circuit simulator: 16 qubits, B=512, 4 layers.
// CNOTs are GF(2) index-relabeling bookkeeping. Fused 1q gates (SU(2)) are
// XOR-mask pair rotations, scheduled into 2 window passes
// (gen+gates+store, load+gates+measure). Within a pass, bundles of 4
// mask-independent gates: each thread applies a bundle on a dim-4 coset
// (16 amps) in registers. AoS LDS (float2 per amp — r6 layout, low bank
// conflicts). Gate math processes 2 independent pairs at once packed into
// v2f lanes -> v_pk_fma_f32: 8 FMA-instr/pair instead of 16.
// Gate coefficients computed in-block (no precompute kernel).

typedef float v2f __attribute__((ext_vector_type(2)));

struct BundleMeta {
    uint16_t voff[16];   // coset offsets (local 12-bit index space)
    uint16_t row[4];     // branch parity masks (local bits), per slot
    uint16_t flip[4];    // flip[g] bit t = parity(voff[t] & row[g])
    uint8_t  piv[4];     // pivot bit positions, ASCENDING (rep expansion)
    uint8_t  gidx[4];    // gate coefficient index l*16+w; 0xFF = identity pad
    uint8_t  nl[4];      // branch parity masks over the 4 chunk bits
};

struct PassMeta {
    int       nbundles;
    BundleMeta bd[24];
    uint8_t   gap[4];          // non-local bit positions, ASCENDING (all >=8)
    uint8_t   nlw[4];          // chunk bit k -> wire
    uint8_t   wire_of_bit[12]; // packed LDS bit -> wire (product-state init)
    uint16_t  meas_row;        // measurement parity mask (local bits)
    uint8_t   meas_nl;         // measurement parity mask (chunk bits)
};

__device__ __forceinline__ float2 cmul2(float2 a, float2 b) {
    return make_float2(a.x * b.x - a.y * b.y, a.x * b.y + a.y * b.x);
}
__device__ __forceinline__ float xorf(float a, unsigned s) {
    return __uint_as_float(__float_as_uint(a) ^ s);
}

// MODE 0: coef + product state + gates + store (fp16)
// MODE 1: coef + load + gates + store (in-place, fp16)
// MODE 2: coef + load + gates + measurement reduce (no store)
template <int MODE>
__global__ __launch_bounds__(256, 4)
void pass_kernel(const float* __restrict__ X, const float* __restrict__ Wt,
                 const float* __restrict__ Bs, __half2* __restrict__ state,
                 float* __restrict__ out, PassMeta meta)
{
    __shared__ v2f    amp[4096];   // 32 KiB, AoS (re,im) per amp
    __shared__ float4 coef[64];    // 1 KiB  (SU(2) (a,b) per gate)
    const int tid = threadIdx.x;
    const int bb  = blockIdx.x >> 4;
    const unsigned c = blockIdx.x & 15u;
    const size_t base = (size_t)bb << 16;

    // ---- in-block coefficients: U = Rz(t2)Ry(t1)Rz(t0)Rx(2atan x), SU(2) (a,b)
    if (tid < 64) {
        int l = tid >> 4, w = tid & 15;
        float x  = X[bb * 16 + w];
        float ce = 1.0f / sqrtf(1.0f + x * x);
        float se = x * ce;
        float t0 = 0.5f * Wt[(l * 16 + w) * 3 + 0];
        float t1 = 0.5f * Wt[(l * 16 + w) * 3 + 1];
        float t2 = 0.5f * Wt[(l * 16 + w) * 3 + 2];
        float c1 = cosf(t1), s1 = sinf(t1);
        float ca = cosf(t0 + t2), sa = sinf(t0 + t2);
        float cb = cosf(t2 - t0), sb = sinf(t2 - t0);
        float2 W00 = make_float2( c1 * ca, -c1 * sa);
        float2 W01 = make_float2(-s1 * cb,  s1 * sb);
        float2 a  = make_float2(W00.x * ce + W01.y * se, W00.y * ce - W01.x * se);
        float2 b2 = make_float2(W00.y * se + W01.x * ce, -W00.x * se + W01.y * ce);
        coef[tid] = make_float4(a.x, a.y, b2.x, b2.y);
    }
    if (MODE == 0 && c == 0 && tid == 64) out[bb] = Bs[0];  // bias init

    auto expand = [&](unsigned x) -> unsigned {   // gaps ascending, all >= 8
        #pragma unroll
        for (int k = 0; k < 4; ++k) {
            unsigned g = meta.gap[k];
            x = ((x >> g) << (g + 1)) | (x & ((1u << g) - 1u)) | (((c >> k) & 1u) << g);
        }
        return x;
    };

    if constexpr (MODE == 0) {
        __syncthreads();   // coef ready
        if (tid == 0) {
            float2 k = make_float2(1.f, 0.f);
            #pragma unroll
            for (int t = 0; t < 4; ++t) {
                float4 u = coef[meta.nlw[t]];
                float2 col = ((c >> t) & 1u) ? make_float2(-u.z, u.w)
                                             : make_float2(u.x, u.y);
                k = cmul2(k, col);
            }
            amp[0] = v2f{k.x, k.y};
        }
        __syncthreads();
        for (int s = 0; s < 12; ++s) {
            const int n = 1 << s;
            float4 u = coef[meta.wire_of_bit[s]];
            const float2 c0 = make_float2(u.x, u.y);
            const float2 c1 = make_float2(-u.z, u.w);
            for (int i = tid; i < n; i += 256) {
                float2 a = make_float2(amp[i].x, amp[i].y);
                float2 h = cmul2(a, c1);
                float2 l = cmul2(a, c0);
                amp[i + n] = v2f{h.x, h.y};
                amp[i]     = v2f{l.x, l.y};
            }
            __syncthreads();
        }
    } else {
        #pragma unroll
        for (int it = 0; it < 4; ++it) {
            unsigned u = (unsigned)(tid + it * 256) * 4u;
            unsigned a = expand(u);
            uint4 v = *reinterpret_cast<const uint4*>(state + base + a);
            float2 f0 = __half22float2(__builtin_bit_cast(__half2, v.x));
            float2 f1 = __half22float2(__builtin_bit_cast(__half2, v.y));
            float2 f2 = __half22float2(__builtin_bit_cast(__half2, v.z));
            float2 f3 = __half22float2(__builtin_bit_cast(__half2, v.w));
            amp[u + 0] = v2f{f0.x, f0.y};
            amp[u + 1] = v2f{f1.x, f1.y};
            amp[u + 2] = v2f{f2.x, f2.y};
            amp[u + 3] = v2f{f3.x, f3.y};
        }
        __syncthreads();   // also covers coef staging
    }

    for (int ci = 0; ci < meta.nbundles; ++ci) {
        const BundleMeta& B = meta.bd[ci];
        unsigned r = (unsigned)tid;
        #pragma unroll
        for (int k = 0; k < 4; ++k) {
            unsigned p = B.piv[k];
            r = ((r >> p) << (p + 1)) | (r & ((1u << p) - 1u));
        }
        float ar_[16], ai_[16];
        #pragma unroll
        for (int t = 0; t < 16; ++t) {
            v2f v = amp[r ^ B.voff[t]];
            ar_[t] = v.x; ai_[t] = v.y;
        }
        #pragma unroll
        for (int g = 0; g < 4; ++g) {
            if (B.gidx[g] == 0xFF) continue;       // identity pad (uniform skip)
            const float4 uv = coef[B.gidx[g]];
            const unsigned sb31 =
                ((unsigned)((__popc(r & (unsigned)B.row[g]) +
                             __popc((unsigned)B.nl[g] & c)) & 1)) << 31;
            const float ai_s = xorf(uv.y, sb31);
            const float br_s = xorf(uv.z, sb31);
            const unsigned fl = B.flip[g];
            const v2f ARv = {uv.x, uv.x};
            const v2f BIv = {uv.w, uv.w};
            // 8 pairs of (t, t|1<<g), processed 2 at a time packed in v2f lanes
            #pragma unroll
            for (int k = 0; k < 4; ++k) {
                const int j0 = 2 * k, j1 = 2 * k + 1;
                const int t0 = ((j0 >> g) << (g + 1)) | (j0 & ((1 << g) - 1));
                const int t1 = ((j1 >> g) << (g + 1)) | (j1 & ((1 << g) - 1));
                const int s0 = t0 | (1 << g), s1 = t1 | (1 << g);
                const unsigned f0 = ((fl >> t0) & 1u) << 31;
                const unsigned f1 = ((fl >> t1) & 1u) << 31;
                const v2f TAI = { xorf(ai_s, f0), xorf(ai_s, f1) };
                const v2f TBR = { xorf(br_s, f0), xorf(br_s, f1) };
                const v2f PR = {ar_[t0], ar_[t1]}, PI = {ai_[t0], ai_[t1]};
                const v2f QR = {ar_[s0], ar_[s1]}, QI = {ai_[s0], ai_[s1]};
                const v2f NPR = ARv * PR - TAI * PI + TBR * QR - BIv * QI;
                const v2f NPI = ARv * PI + TAI * PR + TBR * QI + BIv * QR;
                const v2f NQR = ARv * QR + TAI * QI - TBR * PR - BIv * PI;
                const v2f NQI = ARv * QI - TAI * QR - TBR * PI + BIv * PR;
                ar_[t0] = NPR.x; ar_[t1] = NPR.y;
                ai_[t0] = NPI.x; ai_[t1] = NPI.y;
                ar_[s0] = NQR.x; ar_[s1] = NQR.y;
                ai_[s0] = NQI.x; ai_[s1] = NQI.y;
            }
        }
        if (MODE == 2 && ci == meta.nbundles - 1) {
            // measure directly from registers (skip final LDS round-trip)
            float acc = 0.f;
            const unsigned mcp = (unsigned)(__popc((unsigned)meta.meas_nl & c) & 1);
            #pragma unroll
            for (int t = 0; t < 16; ++t) {
                float pr = __builtin_fmaf(ar_[t], ar_[t], ai_[t] * ai_[t]);
                unsigned sg = ((unsigned)__popc((r ^ B.voff[t]) &
                               (unsigned)meta.meas_row) & 1u) ^ mcp;
                acc += sg ? -pr : pr;
            }
            for (int off = 32; off > 0; off >>= 1) acc += __shfl_down(acc, off, 64);
            if ((tid & 63) == 0) atomicAdd(&out[bb], acc);
            return;
        }
        #pragma unroll
        for (int t = 0; t < 16; ++t)
            amp[r ^ B.voff[t]] = v2f{ar_[t], ai_[t]};
        __syncthreads();
    }

    if constexpr (MODE == 2) {
        // fallback (only if nbundles==0): measure from LDS
        float acc = 0.f;
        const unsigned mcp = (unsigned)(__popc((unsigned)meta.meas_nl & c) & 1);
        for (int k = 0; k < 16; ++k) {
            unsigned u = (unsigned)(tid + k * 256);
            v2f a = amp[u];
            float pr = a.x * a.x + a.y * a.y;
            acc += (((unsigned)__popc(u & (unsigned)meta.meas_row) & 1u) ^ mcp)
                 ? -pr : pr;
        }
        for (int off = 32; off > 0; off >>= 1) acc += __shfl_down(acc, off, 64);
        if ((tid & 63) == 0) atomicAdd(&out[bb], acc);
    } else {
        #pragma unroll
        for (int it = 0; it < 4; ++it) {
            unsigned u = (unsigned)(tid + it * 256) * 4u;
            unsigned ad = expand(u);
            __half2 h0 = __float22half2_rn(make_float2(amp[u + 0].x, amp[u + 0].y));
            __half2 h1 = __float22half2_rn(make_float2(amp[u + 1].x, amp[u + 1].y));
            __half2 h2 = __float22half2_rn(make_float2(amp[u + 2].x, amp[u + 2].y));
            __half2 h3 = __float22half2_rn(make_float2(amp[u + 3].x, amp[u + 3].y));
            uint4 v;
            v.x = __builtin_bit_cast(unsigned, h0);
            v.y = __builtin_bit_cast(unsigned, h1);
            v.z = __builtin_bit_cast(unsigned, h2);
            v.w = __builtin_bit_cast(unsigned, h3);
            *reinterpret_cast<uint4*>(state + base + ad) = v;
        }
    }
}

extern "C" void kernel_launch(void* const* d_in, const int* in_sizes, int n_in,
                              void* d_out, int out_size, void* d_ws, size_t ws_size,
                              hipStream_t stream)
{
    const float* X  = (const float*)d_in[0];
    const float* Wt = (const float*)d_in[1];
    const float* Bs = (const float*)d_in[2];
    float* out = (float*)d_out;
    __half2* state = (__half2*)d_ws;

    int group = 1;   // fp16 state: 256 KiB per batch element
    while (group < 512 && (size_t)(group * 2) * (65536ull * 4) <= ws_size)
        group <<= 1;
    const int ngroups = 512 / group;

    // ---- GF(2) bookkeeping (sequential CNOT ring, matches reference) ----
    uint16_t D[16], R[16];
    for (int w = 0; w < 16; ++w) { D[w] = R[w] = (uint16_t)(1u << w); }
    struct G { uint16_t D, R; uint8_t gidx; bool kept; bool sched; };
    G gl[48]; int ng = 0;
    for (int l = 1; l <= 3; ++l) {
        for (int w = 0; w < 16; ++w) { int t = (w + 1) & 15; D[w] ^= D[t]; R[t] ^= R[w]; }
        for (int w = 0; w < 16; ++w)
            gl[ng++] = G{D[w], R[w], (uint8_t)(l * 16 + w), true, false};
    }
    for (int w = 0; w < 16; ++w) { int t = (w + 1) & 15; D[w] ^= D[t]; R[t] ^= R[w]; }
    const uint16_t Rmeas = R[0];

    // Backward prune
    {
        uint16_t keptD[49], keptR[49]; int nk = 0;
        keptD[nk] = 0; keptR[nk] = Rmeas; ++nk;
        for (int i = ng - 1; i >= 0; --i) {
            bool comm = true;
            for (int k = 0; k < nk; ++k) {
                if (__builtin_parity((unsigned)(gl[i].D & keptR[k])) ||
                    __builtin_parity((unsigned)(keptD[k] & gl[i].R))) { comm = false; break; }
            }
            if (comm) gl[i].kept = false;
            else { keptD[nk] = gl[i].D; keptR[nk] = gl[i].R; ++nk; }
        }
    }
    int nkept = 0;
    for (int i = 0; i < ng; ++i) if (gl[i].kept) ++nkept;

    auto commute = [&](int i, int j) -> bool {
        return !(__builtin_parity((unsigned)(gl[i].D & gl[j].R)) ||
                 __builtin_parity((unsigned)(gl[j].D & gl[i].R)));
    };

    const int MAXP = 8;
    auto simulate = [&](uint16_t SA, uint16_t SB, int* passOf) -> int {
        for (int i = 0; i < ng; ++i) gl[i].sched = false;
        int rem = nkept, np = 0, stall = 0;
        while (rem > 0 && np < MAXP) {
            uint16_t S = (np & 1) ? SB : SA;
            int got = 0;
            for (int i = 0; i < ng; ++i) {
                if (!gl[i].kept || gl[i].sched) continue;
                if (gl[i].D & S) continue;
                bool ok = true;
                for (int j = 0; j < i; ++j) {
                    if (!gl[j].kept || gl[j].sched) continue;
                    if (!commute(i, j)) { ok = false; break; }
                }
                if (!ok) continue;
                gl[i].sched = true; --rem; ++got;
                if (passOf) passOf[i] = np;
            }
            ++np;
            if (got == 0) { if (++stall >= 2) break; } else stall = 0;
        }
        return rem == 0 ? np : 99;
    };

    // Window-pair search (4 excluded wires per window, consecutive runs)
    int bestNp = 99, bestA = 0, bestB = 8;
    for (int a = 0; a < 16; ++a) {
        for (int b = 0; b < 16; ++b) {
            uint16_t SA = 0, SB = 0;
            for (int k = 0; k < 4; ++k) {
                SA |= (uint16_t)(1u << ((a + k) & 15));
                SB |= (uint16_t)(1u << ((b + k) & 15));
            }
            int np = simulate(SA, SB, nullptr);
            if (np < bestNp) { bestNp = np; bestA = a; bestB = b; }
        }
    }
    uint16_t SA = 0, SB = 0;
    int exA[4], exB[4];
    for (int k = 0; k < 4; ++k) {
        exA[k] = (bestA + k) & 15; exB[k] = (bestB + k) & 15;
        SA |= (uint16_t)(1u << exA[k]); SB |= (uint16_t)(1u << exB[k]);
    }
    int passOf[48];
    for (int i = 0; i < ng; ++i) passOf[i] = -1;
    int np = simulate(SA, SB, passOf);
    if (np > MAXP) np = MAXP;
    if (np < 2) np = 2;

    // Wire -> bit position: all excluded wires at positions >= 8.
    int wireToPos[16]; bool used[16] = {};
    int pos = 15;
    for (int k = 0; k < 4; ++k) { wireToPos[exA[k]] = pos--; used[exA[k]] = true; }
    for (int k = 0; k < 4; ++k)
        if (!used[exB[k]]) { wireToPos[exB[k]] = pos--; used[exB[k]] = true; }
    for (int w = 0; w < 16; ++w) if (!used[w]) wireToPos[w] = pos--;
    int posToWire[16];
    for (int w = 0; w < 16; ++w) posToWire[wireToPos[w]] = w;

    PassMeta pms[8];
    for (int p = 0; p < np; ++p) {
        PassMeta& M = pms[p];
        memset(&M, 0, sizeof(M));
        const int* ex = (p & 1) ? exB : exA;
        int gp[4], gw[4];
        for (int k = 0; k < 4; ++k) { gp[k] = wireToPos[ex[k]]; gw[k] = ex[k]; }
        for (int a2 = 0; a2 < 4; ++a2)
            for (int b2 = a2 + 1; b2 < 4; ++b2)
                if (gp[b2] < gp[a2]) {
                    int t = gp[a2]; gp[a2] = gp[b2]; gp[b2] = t;
                    t = gw[a2]; gw[a2] = gw[b2]; gw[b2] = t;
                }
        for (int k = 0; k < 4; ++k) { M.gap[k] = (uint8_t)gp[k]; M.nlw[k] = (uint8_t)gw[k]; }
        int packedOfWire[16];
        for (int w = 0; w < 16; ++w) packedOfWire[w] = -1;
        int t = 0;
        for (int q = 0; q < 16; ++q) {
            bool isgap = false;
            for (int k = 0; k < 4; ++k) if (q == gp[k]) isgap = true;
            if (isgap) continue;
            M.wire_of_bit[t] = (uint8_t)posToWire[q];
            packedOfWire[posToWire[q]] = t;
            ++t;
        }
        // local gate list (order preserved from simulate's schedule order)
        struct LG { uint16_t m, r; uint8_t nl, gidx; };
        LG ls[48]; int nsel = 0;
        for (int i = 0; i < ng; ++i) {
            if (!gl[i].kept || passOf[i] != p) continue;
            uint16_t m = 0, r = 0; uint8_t nl = 0;
            for (int w = 0; w < 16; ++w) {
                if ((gl[i].D >> w) & 1) m |= (uint16_t)(1u << packedOfWire[w]);
                if (((gl[i].R >> w) & 1) && packedOfWire[w] >= 0)
                    r |= (uint16_t)(1u << packedOfWire[w]);
            }
            for (int k = 0; k < 4; ++k)
                if ((gl[i].R >> gw[k]) & 1) nl |= (uint8_t)(1u << k);
            ls[nsel++] = LG{m, r, nl, gl[i].gidx};
        }
        // bundle into groups of <=4 with independent masks (consecutive)
        M.nbundles = 0;
        int s = 0;
        while (s < nsel && M.nbundles < 24) {
            BundleMeta& B = M.bd[M.nbundles++];
            for (int j = 0; j < 4; ++j) {
                B.gidx[j] = 0xFF; B.row[j] = 0; B.flip[j] = 0; B.nl[j] = 0;
            }
            uint16_t red[4], om[4]; int pv[4]; int nsl = 0;
            while (nsl < 4 && s < nsel) {
                uint16_t r0 = ls[s].m;
                for (int j = 0; j < nsl; ++j)
                    if ((r0 >> pv[j]) & 1) r0 ^= red[j];
                if (!r0) break;    // dependent -> close bundle
                pv[nsl] = 31 - __builtin_clz((unsigned)r0);
                red[nsl] = r0; om[nsl] = ls[s].m;
                B.gidx[nsl] = ls[s].gidx; B.row[nsl] = ls[s].r; B.nl[nsl] = ls[s].nl;
                ++nsl; ++s;
            }
            for (int b = 11; b >= 0 && nsl < 4; --b) {   // pad basis
                uint16_t r0 = (uint16_t)(1u << b);
                for (int j = 0; j < nsl; ++j)
                    if ((r0 >> pv[j]) & 1) r0 ^= red[j];
                if (!r0) continue;
                pv[nsl] = 31 - __builtin_clz((unsigned)r0);
                red[nsl] = r0; om[nsl] = (uint16_t)(1u << b);
                ++nsl;
            }
            for (int tt = 0; tt < 16; ++tt) {
                uint16_t v = 0;
                for (int j = 0; j < 4; ++j) if ((tt >> j) & 1) v ^= om[j];
                B.voff[tt] = v;
            }
            for (int j = 0; j < 4; ++j) {
                if (B.gidx[j] == 0xFF) continue;
                uint16_t f = 0;
                for (int tt = 0; tt < 16; ++tt)
                    if (__builtin_parity((unsigned)(B.voff[tt] & B.row[j])))
                        f |= (uint16_t)(1u << tt);
                B.flip[j] = f;
            }
            for (int a2 = 0; a2 < 4; ++a2)
                for (int b2 = a2 + 1; b2 < 4; ++b2)
                    if (pv[b2] < pv[a2]) { int tt = pv[a2]; pv[a2] = pv[b2]; pv[b2] = tt; }
            for (int j = 0; j < 4; ++j) B.piv[j] = (uint8_t)pv[j];
        }
        {   // measurement masks (used only if this pass is last)
            uint16_t r = 0; uint8_t nl = 0;
            for (int w = 0; w < 16; ++w)
                if (((Rmeas >> w) & 1) && packedOfWire[w] >= 0)
                    r |= (uint16_t)(1u << packedOfWire[w]);
            for (int k = 0; k < 4; ++k)
                if ((Rmeas >> gw[k]) & 1) nl |= (uint8_t)(1u << k);
            M.meas_row = r; M.meas_nl = nl;
        }
    }

    for (int g = 0; g < ngroups; ++g) {
        const float* Xg = X + (size_t)g * group * 16;
        float* og = out + (size_t)g * group;
        dim3 grid((unsigned)(group << 4));
        for (int p = 0; p < np; ++p) {
            int mode = (p == 0) ? 0 : ((p == np - 1) ? 2 : 1);
            if (mode == 0)
                pass_kernel<0><<<grid, dim3(256), 0, stream>>>(Xg, Wt, Bs, state, og, pms[p]);
            else if (mode == 1)
                pass_kernel<1><<<grid, dim3(256), 0, stream>>>(Xg, Wt, Bs, state, og, pms[p]);
            else
                pass_kernel<2><<<grid, dim3(256), 0, stream>>>(Xg, Wt, Bs, state, og, pms[p]);
        }
    }

    (void)in_sizes; (void)n_in; (void)out_size; (void)ws_size;
}